// Round 3
// baseline (769.017 us; speedup 1.0000x reference)
//
#include <hip/hip_runtime.h>
#include <math.h>

#define NN 262144
#define DD 256

typedef __attribute__((ext_vector_type(8))) _Float16 h16x8;  // 8 fp16 = 4 VGPRs
typedef __attribute__((ext_vector_type(4))) float f32x4;

#define MFMA16 __builtin_amdgcn_mfma_f32_16x16x32_f16

// halfword-granular XOR swizzle: conflict-free b128 on fp16 [64][256] tiles
__device__ __forceinline__ int swz16(int row, int k) {
  return (row << 8) + ((((k >> 3) ^ (row & 7)) << 3) | (k & 7));
}
// float-granular XOR swizzle: conflict-free b128 on fp32 [64][256] tiles
__device__ __forceinline__ int swzf(int row, int k) {
  return (row << 8) + ((((k >> 2) ^ (row & 7)) << 2) | (k & 3));
}

// fp16 2-way split: a = hi + lo*2^-12 (+ O(2^-23)|a|); lo pre-scaled 2^12
__device__ __forceinline__ void hsplit(float a, unsigned short& hb, unsigned short& lb) {
  _Float16 h = (_Float16)a;                 // RN
  float r = a - (float)h;                   // exact
  _Float16 l = (_Float16)(r * 4096.f);      // scaled: no fp16 denormals
  hb = __builtin_bit_cast(unsigned short, h);
  lb = __builtin_bit_cast(unsigned short, l);
}

// A&S 7.1.26 erf: |err| <= 1.5e-7 absolute, branchless, ~16 VALU
__device__ __forceinline__ float gelu_fast(float x) {
  float z  = fabsf(x) * 0.70710678118654752f;
  float t  = __builtin_amdgcn_rcpf(fmaf(0.3275911f, z, 1.f));
  float P  = t * fmaf(t, fmaf(t, fmaf(t, fmaf(t, 1.061405429f, -1.453152027f),
                                      1.421413741f), -0.284496736f), 0.254829592f);
  float E  = __builtin_amdgcn_exp2f(-1.442695041f * z * z);
  float er = fmaf(-P, E, 1.f);              // erf(|z|)
  return 0.5f * x * (1.f + copysignf(er, x));
}

// ---------------- prep: fp16 2-way split of W1 (lo scaled 2^12) -------------
__global__ void prep_kernel(const float* __restrict__ W1,
                            unsigned short* __restrict__ wh,
                            unsigned short* __restrict__ wl) {
  int t = blockIdx.x * 256 + threadIdx.x;
  unsigned short hb, lb;
  hsplit(W1[t], hb, lb);
  wh[t] = hb;
  wl[t] = lb;
}

// ---------------- fused MLP: gelu(A@W1^T+b1)@W2^T + b2 -> M [N][9] ----------
__global__ __launch_bounds__(512, 4) void mlp_kernel(
    const float* __restrict__ A, const float* __restrict__ b1,
    const float* __restrict__ b2, const float* __restrict__ W2,
    const unsigned short* __restrict__ w1h, const unsigned short* __restrict__ w1l,
    float* __restrict__ Mout)
{
  __shared__ unsigned short sbuf[32768];     // 64 KB: A-split fp16, later h fp32
  unsigned short* sH = sbuf;                 // 32 KB hi
  unsigned short* sL = sbuf + 16384;         // 32 KB lo (scaled 2^12)
  float* sF = (float*)sbuf;                  // 64 KB h (phase 2)

  const int tid  = threadIdx.x;
  const int lane = tid & 63;
  const int wv   = tid >> 6;                 // wave 0..7 -> 32-col strip
  const int n0   = blockIdx.x * 64;

  // ---- stage A tile [64][256] fp32 -> fp16 hi/lo in LDS ----
  const float4* A4 = (const float4*)(A + (size_t)n0 * DD);
  #pragma unroll
  for (int it = 0; it < 8; ++it) {
    int f   = (it << 9) + tid;               // 0..4095 float4s
    int row = f >> 6;
    int kc  = (f & 63) << 2;
    float4 v = A4[f];
    ushort4 hv, lv;
    hsplit(v.x, hv.x, lv.x);
    hsplit(v.y, hv.y, lv.y);
    hsplit(v.z, hv.z, lv.z);
    hsplit(v.w, hv.w, lv.w);
    int idx = swz16(row, kc);                // kc%8 in {0,4}: stays in chunk
    *(ushort4*)&sH[idx] = hv;
    *(ushort4*)&sL[idx] = lv;
  }
  __syncthreads();

  const int m  = lane & 15;
  const int g  = lane >> 4;
  const int kq = g << 3;

  f32x4 acc0[4][2], acc1[4][2];
  #pragma unroll
  for (int r = 0; r < 4; ++r)
    #pragma unroll
    for (int c = 0; c < 2; ++c) {
      acc0[r][c] = (f32x4){0.f, 0.f, 0.f, 0.f};
      acc1[r][c] = (f32x4){0.f, 0.f, 0.f, 0.f};
    }

  const int bcol0 = (wv * 32 + m) * DD + kq;       // c=0 column
  const int bcol1 = (wv * 32 + 16 + m) * DD + kq;  // c=1 column

  #pragma unroll
  for (int ks = 0; ks < 8; ++ks) {
    h16x8 Bh[2], Bl[2];
    Bh[0] = *(const h16x8*)(w1h + bcol0 + ks * 32);
    Bh[1] = *(const h16x8*)(w1h + bcol1 + ks * 32);
    Bl[0] = *(const h16x8*)(w1l + bcol0 + ks * 32);
    Bl[1] = *(const h16x8*)(w1l + bcol1 + ks * 32);
    #pragma unroll
    for (int r = 0; r < 4; ++r) {
      int ai = swz16(r * 16 + m, ks * 32 + kq);
      h16x8 Ah = *(const h16x8*)&sH[ai];
      h16x8 Al = *(const h16x8*)&sL[ai];
      #pragma unroll
      for (int c = 0; c < 2; ++c) {
        // two independent chains per (r,c): hi*hi ; (lo*hi + hi*lo) scaled 2^12
        acc1[r][c] = MFMA16(Al, Bh[c], acc1[r][c], 0, 0, 0);
        acc1[r][c] = MFMA16(Ah, Bl[c], acc1[r][c], 0, 0, 0);
        acc0[r][c] = MFMA16(Ah, Bh[c], acc0[r][c], 0, 0, 0);
      }
    }
  }
  __syncthreads();   // all A reads done before h overwrites LDS

  // ---- epilogue: combine accs, +b1, fast exact-grade GELU, h fp32 -> LDS ----
  #pragma unroll
  for (int c = 0; c < 2; ++c) {
    int j = wv * 32 + c * 16 + m;
    float bias = b1[j];
    #pragma unroll
    for (int r = 0; r < 4; ++r) {
      #pragma unroll
      for (int ri = 0; ri < 4; ++ri) {
        float x = fmaf(acc1[r][c][ri], 2.44140625e-4f, acc0[r][c][ri]) + bias;
        sF[swzf(r * 16 + g * 4 + ri, j)] = gelu_fast(x);
      }
    }
  }
  __syncthreads();

  // ---- GEMM2 fp32 VALU + in-wave shfl reduce: h[64][256] @ W2^T -> M[64][9]
  const int rloc = lane >> 3;                // 0..7
  const int row  = wv * 8 + rloc;            // 0..63
  const int kc   = (lane & 7) << 5;          // 32-wide K strip per lane
  float aj[9];
  #pragma unroll
  for (int j = 0; j < 9; ++j) aj[j] = 0.f;
  #pragma unroll
  for (int kk = 0; kk < 32; kk += 4) {
    float4 h4 = *(const float4*)&sF[swzf(row, kc + kk)];
    #pragma unroll
    for (int j = 0; j < 9; ++j) {
      float4 w = *(const float4*)(W2 + j * DD + kc + kk);
      aj[j] = fmaf(h4.x, w.x, fmaf(h4.y, w.y, fmaf(h4.z, w.z, fmaf(h4.w, w.w, aj[j]))));
    }
  }
  #pragma unroll
  for (int off = 1; off < 8; off <<= 1)
    #pragma unroll
    for (int j = 0; j < 9; ++j)
      aj[j] += __shfl_xor(aj[j], off, 64);
  if ((lane & 7) == 0) {
    float* op = Mout + (size_t)(n0 + row) * 9;
    #pragma unroll
    for (int j = 0; j < 9; ++j) op[j] = aj[j] + b2[j];
  }
}

// ---------------- procrustes: Horn quaternion, fp32 Jacobi + fp64 refine ----
template <int P, int Q>
__device__ __forceinline__ void jrot(float Aq[4][4], float V[4][4]) {
  float apq = Aq[P][Q];
  float d   = Aq[Q][Q] - Aq[P][P];
  float sq  = sqrtf(d * d + 4.f * apq * apq);
  float den = fmaxf(fabsf(d) + sq, 1e-35f);
  float tt  = 2.f * apq * copysignf(1.f, d) / den;
  float c   = rsqrtf(1.f + tt * tt);
  float s   = tt * c;
  float app = Aq[P][P], aqq = Aq[Q][Q];
  Aq[P][P] = app - tt * apq;
  Aq[Q][Q] = aqq + tt * apq;
  Aq[P][Q] = 0.f; Aq[Q][P] = 0.f;
  #pragma unroll
  for (int r = 0; r < 4; ++r) {
    if (r == P || r == Q) continue;
    float arp = Aq[r][P], arq = Aq[r][Q];
    Aq[r][P] = Aq[P][r] = c * arp - s * arq;
    Aq[r][Q] = Aq[Q][r] = s * arp + c * arq;
  }
  #pragma unroll
  for (int i = 0; i < 4; ++i) {
    float vp = V[i][P], vq = V[i][Q];
    V[i][P] = c * vp - s * vq;
    V[i][Q] = s * vp + c * vq;
  }
}

__device__ __forceinline__ double det3(double a, double b, double c,
                                       double d, double e, double f,
                                       double g, double h, double i) {
  return a * (e * i - f * h) - b * (d * i - f * g) + c * (d * h - e * g);
}

__global__ __launch_bounds__(256) void procrustes_kernel(const float* __restrict__ M,
                                                         float* __restrict__ out) {
  int t = blockIdx.x * 256 + threadIdx.x;
  const float* mp = M + (size_t)t * 9;
  float m00 = mp[0], m01 = mp[1], m02 = mp[2];
  float m10 = mp[3], m11 = mp[4], m12 = mp[5];
  float m20 = mp[6], m21 = mp[7], m22 = mp[8];

  float Aq[4][4], V[4][4];
  Aq[0][0] =  m00 + m11 + m22;
  Aq[1][1] =  m00 - m11 - m22;
  Aq[2][2] = -m00 + m11 - m22;
  Aq[3][3] = -m00 - m11 + m22;
  Aq[0][1] = Aq[1][0] = m21 - m12;
  Aq[0][2] = Aq[2][0] = m02 - m20;
  Aq[0][3] = Aq[3][0] = m10 - m01;
  Aq[1][2] = Aq[2][1] = m01 + m10;
  Aq[1][3] = Aq[3][1] = m02 + m20;
  Aq[2][3] = Aq[3][2] = m12 + m21;
  #pragma unroll
  for (int i = 0; i < 4; ++i)
    #pragma unroll
    for (int j = 0; j < 4; ++j)
      V[i][j] = (i == j) ? 1.f : 0.f;

  #pragma unroll
  for (int sweep = 0; sweep < 5; ++sweep) {
    jrot<0,1>(Aq, V); jrot<0,2>(Aq, V); jrot<0,3>(Aq, V);
    jrot<1,2>(Aq, V); jrot<1,3>(Aq, V); jrot<2,3>(Aq, V);
  }

  float bv = Aq[0][0];
  float qw = V[0][0], qx = V[1][0], qy = V[2][0], qz = V[3][0];
  #define PICK(K) if (Aq[K][K] > bv) { bv = Aq[K][K]; qw = V[0][K]; qx = V[1][K]; qy = V[2][K]; qz = V[3][K]; }
  PICK(1) PICK(2) PICK(3)
  #undef PICK

  // fp64 Rayleigh-shift + adjugate inverse-iteration refinement
  double d00 = (double)m00, d01 = (double)m01, d02 = (double)m02;
  double d10 = (double)m10, d11 = (double)m11, d12 = (double)m12;
  double d20 = (double)m20, d21 = (double)m21, d22 = (double)m22;
  double Nd[4][4];
  Nd[0][0] =  d00 + d11 + d22;
  Nd[1][1] =  d00 - d11 - d22;
  Nd[2][2] = -d00 + d11 - d22;
  Nd[3][3] = -d00 - d11 + d22;
  Nd[0][1] = Nd[1][0] = d21 - d12;
  Nd[0][2] = Nd[2][0] = d02 - d20;
  Nd[0][3] = Nd[3][0] = d10 - d01;
  Nd[1][2] = Nd[2][1] = d01 + d10;
  Nd[1][3] = Nd[3][1] = d02 + d20;
  Nd[2][3] = Nd[3][2] = d12 + d21;

  double qd[4] = {(double)qw, (double)qx, (double)qy, (double)qz};
  double nn = qd[0]*qd[0] + qd[1]*qd[1] + qd[2]*qd[2] + qd[3]*qd[3];
  double Nq[4];
  #pragma unroll
  for (int i = 0; i < 4; ++i)
    Nq[i] = Nd[i][0]*qd[0] + Nd[i][1]*qd[1] + Nd[i][2]*qd[2] + Nd[i][3]*qd[3];
  double sig = (qd[0]*Nq[0] + qd[1]*Nq[1] + qd[2]*Nq[2] + qd[3]*Nq[3]) / nn;

  double Ad[4][4];
  #pragma unroll
  for (int i = 0; i < 4; ++i)
    #pragma unroll
    for (int j = 0; j < 4; ++j)
      Ad[i][j] = Nd[i][j] - (i == j ? sig : 0.0);

  double y[4];
  #pragma unroll
  for (int i = 0; i < 4; ++i) {
    double yi = 0.0;
    #pragma unroll
    for (int j = 0; j < 4; ++j) {
      const int r0 = (i == 0) ? 1 : 0, r1 = (i <= 1) ? 2 : 1, r2 = (i <= 2) ? 3 : 2;
      const int c0 = (j == 0) ? 1 : 0, c1 = (j <= 1) ? 2 : 1, c2 = (j <= 2) ? 3 : 2;
      double mnr = det3(Ad[r0][c0], Ad[r0][c1], Ad[r0][c2],
                        Ad[r1][c0], Ad[r1][c1], Ad[r1][c2],
                        Ad[r2][c0], Ad[r2][c1], Ad[r2][c2]);
      double s = ((i + j) & 1) ? -mnr : mnr;
      yi += s * qd[j];
    }
    y[i] = yi;
  }
  double yn = y[0]*y[0] + y[1]*y[1] + y[2]*y[2] + y[3]*y[3];
  if (!(yn > 1e-280)) { y[0] = qd[0]; y[1] = qd[1]; y[2] = qd[2]; y[3] = qd[3]; yn = nn; }
  double inv = 1.0 / sqrt(yn);
  double w = y[0]*inv, x = y[1]*inv, yv = y[2]*inv, z = y[3]*inv;

  double xx = x*x, yy = yv*yv, zz = z*z;
  double xy = x*yv, xz = x*z, yz = yv*z;
  double wx = w*x, wy = w*yv, wz = w*z;

  float* op = out + (size_t)t * 9;
  op[0] = (float)(1.0 - 2.0*(yy + zz));
  op[1] = (float)(2.0*(xy - wz));
  op[2] = (float)(2.0*(xz + wy));
  op[3] = (float)(2.0*(xy + wz));
  op[4] = (float)(1.0 - 2.0*(xx + zz));
  op[5] = (float)(2.0*(yz - wx));
  op[6] = (float)(2.0*(xz - wy));
  op[7] = (float)(2.0*(yz + wx));
  op[8] = (float)(1.0 - 2.0*(xx + yy));
}

extern "C" void kernel_launch(void* const* d_in, const int* in_sizes, int n_in,
                              void* d_out, int out_size, void* d_ws, size_t ws_size,
                              hipStream_t stream) {
  const float* bb = (const float*)d_in[0];
  const float* W1 = (const float*)d_in[1];
  const float* b1 = (const float*)d_in[2];
  const float* W2 = (const float*)d_in[3];
  const float* b2 = (const float*)d_in[4];
  float* out = (float*)d_out;
  char* ws = (char*)d_ws;
  // ws: w1h[128K] w1l[128K] M[9.44MB]
  unsigned short* w1h = (unsigned short*)(ws);
  unsigned short* w1l = (unsigned short*)(ws + 131072);
  float* Mbuf = (float*)(ws + 262144);

  hipLaunchKernelGGL(prep_kernel, dim3(256), dim3(256), 0, stream, W1, w1h, w1l);
  hipLaunchKernelGGL(mlp_kernel, dim3(NN / 64), dim3(512), 0, stream,
                     bb, b1, b2, W2, w1h, w1l, Mbuf);
  hipLaunchKernelGGL(procrustes_kernel, dim3(NN / 256), dim3(256), 0, stream, Mbuf, out);
}

// Round 4
// 524.357 us; speedup vs baseline: 1.4666x; 1.4666x over previous
//
#include <hip/hip_runtime.h>
#include <math.h>

#define NN 262144
#define DD 256

typedef __attribute__((ext_vector_type(8))) _Float16 h16x8;  // 8 fp16 = 4 VGPRs
typedef __attribute__((ext_vector_type(4))) float f32x4;

#define MFMA16 __builtin_amdgcn_mfma_f32_16x16x32_f16

// halfword-granular XOR swizzle: conflict-free b128 on fp16 [64][256] tiles
__device__ __forceinline__ int swz16(int row, int k) {
  return (row << 8) + ((((k >> 3) ^ (row & 7)) << 3) | (k & 7));
}

// fp16 2-way split: a = hi + lo*2^-12 (+ O(2^-23)|a|); lo pre-scaled 2^12
__device__ __forceinline__ void hsplit(float a, unsigned short& hb, unsigned short& lb) {
  _Float16 h = (_Float16)a;                 // RN
  float r = a - (float)h;                   // exact (Sterbenz)
  _Float16 l = (_Float16)(r * 4096.f);      // scaled: no fp16 denormals
  hb = __builtin_bit_cast(unsigned short, h);
  lb = __builtin_bit_cast(unsigned short, l);
}

// A&S 7.1.26 erf: |err| <= 1.5e-7 absolute, branchless, ~16 VALU
__device__ __forceinline__ float gelu_fast(float x) {
  float z  = fabsf(x) * 0.70710678118654752f;
  float t  = __builtin_amdgcn_rcpf(fmaf(0.3275911f, z, 1.f));
  float P  = t * fmaf(t, fmaf(t, fmaf(t, fmaf(t, 1.061405429f, -1.453152027f),
                                      1.421413741f), -0.284496736f), 0.254829592f);
  float E  = __builtin_amdgcn_exp2f(-1.442695041f * z * z);
  float er = fmaf(-P, E, 1.f);              // erf(|z|)
  return 0.5f * x * (1.f + copysignf(er, x));
}

// ---- prep: fp16 2-way split of W1 [256][256] and W2 padded to [16][256] ----
__global__ void prep_kernel(const float* __restrict__ W1, const float* __restrict__ W2,
                            unsigned short* __restrict__ w1h, unsigned short* __restrict__ w1l,
                            unsigned short* __restrict__ w2h, unsigned short* __restrict__ w2l) {
  int t = blockIdx.x * 256 + threadIdx.x;
  if (t < 65536) {
    unsigned short hb, lb;
    hsplit(W1[t], hb, lb);
    w1h[t] = hb;
    w1l[t] = lb;
  } else {
    int i = t - 65536;                      // [16][256] padded W2
    float v = (i < 9 * DD) ? W2[i] : 0.f;
    unsigned short hb, lb;
    hsplit(v, hb, lb);
    w2h[i] = hb;
    w2l[i] = lb;
  }
}

// ---------------- fused MLP: gelu(A@W1^T+b1)@W2^T + b2 -> M [N][9] ----------
__global__ __launch_bounds__(256, 2) void mlp_kernel(
    const float* __restrict__ A, const float* __restrict__ b1,
    const float* __restrict__ b2,
    const unsigned short* __restrict__ w1h, const unsigned short* __restrict__ w1l,
    const unsigned short* __restrict__ w2h, const unsigned short* __restrict__ w2l,
    float* __restrict__ Mout)
{
  __shared__ unsigned short sbuf[32768];     // 64 KB total
  unsigned short* sH = sbuf;                 // 32 KB: A hi (later h hi)
  unsigned short* sL = sbuf + 16384;         // 32 KB: A lo (later h lo), x4096

  const int tid  = threadIdx.x;
  const int lane = tid & 63;
  const int wv   = tid >> 6;                 // wave 0..3 -> 64-col strip
  const int n0   = blockIdx.x * 64;

  // ---- stage A tile [64][256] fp32 -> fp16 hi/lo in LDS (split ONCE) ----
  const float4* A4 = (const float4*)(A + (size_t)n0 * DD);
  #pragma unroll
  for (int it = 0; it < 16; ++it) {
    int f   = (it << 8) + tid;               // 0..4095 float4s, coalesced
    int row = f >> 6;
    int kc  = (f & 63) << 2;
    float4 v = A4[f];
    ushort4 hv, lv;
    hsplit(v.x, hv.x, lv.x);
    hsplit(v.y, hv.y, lv.y);
    hsplit(v.z, hv.z, lv.z);
    hsplit(v.w, hv.w, lv.w);
    int idx = swz16(row, kc);                // kc%8 in {0,4}: stays in chunk
    *(ushort4*)&sH[idx] = hv;
    *(ushort4*)&sL[idx] = lv;
  }
  __syncthreads();

  const int m  = lane & 15;
  const int g  = lane >> 4;
  const int kq = g << 3;

  // ---- GEMM1: 4x4 tiles/wave, 3-product emulated fp32, 2 indep chains ----
  f32x4 acc0[4][4], acc1[4][4];
  #pragma unroll
  for (int r = 0; r < 4; ++r)
    #pragma unroll
    for (int c = 0; c < 4; ++c) {
      acc0[r][c] = (f32x4){0.f, 0.f, 0.f, 0.f};
      acc1[r][c] = (f32x4){0.f, 0.f, 0.f, 0.f};
    }

  int boff[4];
  #pragma unroll
  for (int c = 0; c < 4; ++c) boff[c] = (wv * 64 + c * 16 + m) * DD + kq;

  #pragma unroll
  for (int ks = 0; ks < 8; ++ks) {
    h16x8 Bh[4], Bl[4];
    #pragma unroll
    for (int c = 0; c < 4; ++c) {
      Bh[c] = *(const h16x8*)(w1h + boff[c] + ks * 32);
      Bl[c] = *(const h16x8*)(w1l + boff[c] + ks * 32);
    }
    h16x8 Ah[4], Al[4];
    #pragma unroll
    for (int r = 0; r < 4; ++r) {
      int ai = swz16(r * 16 + m, ks * 32 + kq);
      Ah[r] = *(const h16x8*)&sH[ai];
      Al[r] = *(const h16x8*)&sL[ai];
    }
    #pragma unroll
    for (int r = 0; r < 4; ++r)
      #pragma unroll
      for (int c = 0; c < 4; ++c) {
        acc1[r][c] = MFMA16(Al[r], Bh[c], acc1[r][c], 0, 0, 0);
        acc1[r][c] = MFMA16(Ah[r], Bl[c], acc1[r][c], 0, 0, 0);
        acc0[r][c] = MFMA16(Ah[r], Bh[c], acc0[r][c], 0, 0, 0);
      }
  }
  __syncthreads();   // all A reads done before h overwrites LDS

  // ---- epilogue: combine chains, +b1, fast GELU, re-split h -> LDS ----
  #pragma unroll
  for (int c = 0; c < 4; ++c) {
    int j = wv * 64 + c * 16 + m;
    float bias = b1[j];
    #pragma unroll
    for (int r = 0; r < 4; ++r) {
      #pragma unroll
      for (int ri = 0; ri < 4; ++ri) {
        float x  = fmaf(acc1[r][c][ri], 2.44140625e-4f, acc0[r][c][ri]) + bias;
        float gl = gelu_fast(x);
        unsigned short hb, lb;
        hsplit(gl, hb, lb);
        int idx = swz16(r * 16 + g * 4 + ri, j);
        sH[idx] = hb;
        sL[idx] = lb;
      }
    }
  }
  __syncthreads();

  // ---- GEMM2 via MFMA: h[64][256] @ W2split^T(16-pad) -> M; wave=16 rows ----
  f32x4 accM0 = (f32x4){0.f, 0.f, 0.f, 0.f};
  f32x4 accM1 = (f32x4){0.f, 0.f, 0.f, 0.f};
  const int w2off = m * DD + kq;             // B col = m (j index, 16-padded)
  #pragma unroll
  for (int ks = 0; ks < 8; ++ks) {
    int ai = swz16(wv * 16 + m, ks * 32 + kq);
    h16x8 Ah = *(const h16x8*)&sH[ai];
    h16x8 Al = *(const h16x8*)&sL[ai];
    h16x8 Wh = *(const h16x8*)(w2h + w2off + ks * 32);
    h16x8 Wl = *(const h16x8*)(w2l + w2off + ks * 32);
    accM1 = MFMA16(Al, Wh, accM1, 0, 0, 0);
    accM1 = MFMA16(Ah, Wl, accM1, 0, 0, 0);
    accM0 = MFMA16(Ah, Wh, accM0, 0, 0, 0);
  }
  if (m < 9) {
    float bq = b2[m];
    #pragma unroll
    for (int ri = 0; ri < 4; ++ri) {
      int row = wv * 16 + g * 4 + ri;        // C layout: row=(lane>>4)*4+reg
      float val = fmaf(accM1[ri], 2.44140625e-4f, accM0[ri]) + bq;
      Mout[(size_t)(n0 + row) * 9 + m] = val;
    }
  }
}

// ---------------- procrustes: Horn quaternion, fp32 Jacobi + fp64 refine ----
template <int P, int Q>
__device__ __forceinline__ void jrot(float Aq[4][4], float V[4][4]) {
  float apq = Aq[P][Q];
  float d   = Aq[Q][Q] - Aq[P][P];
  float sq  = sqrtf(d * d + 4.f * apq * apq);
  float den = fmaxf(fabsf(d) + sq, 1e-35f);
  float tt  = 2.f * apq * copysignf(1.f, d) / den;
  float c   = rsqrtf(1.f + tt * tt);
  float s   = tt * c;
  float app = Aq[P][P], aqq = Aq[Q][Q];
  Aq[P][P] = app - tt * apq;
  Aq[Q][Q] = aqq + tt * apq;
  Aq[P][Q] = 0.f; Aq[Q][P] = 0.f;
  #pragma unroll
  for (int r = 0; r < 4; ++r) {
    if (r == P || r == Q) continue;
    float arp = Aq[r][P], arq = Aq[r][Q];
    Aq[r][P] = Aq[P][r] = c * arp - s * arq;
    Aq[r][Q] = Aq[Q][r] = s * arp + c * arq;
  }
  #pragma unroll
  for (int i = 0; i < 4; ++i) {
    float vp = V[i][P], vq = V[i][Q];
    V[i][P] = c * vp - s * vq;
    V[i][Q] = s * vp + c * vq;
  }
}

__device__ __forceinline__ double det3(double a, double b, double c,
                                       double d, double e, double f,
                                       double g, double h, double i) {
  return a * (e * i - f * h) - b * (d * i - f * g) + c * (d * h - e * g);
}

__global__ __launch_bounds__(256) void procrustes_kernel(const float* __restrict__ M,
                                                         float* __restrict__ out) {
  int t = blockIdx.x * 256 + threadIdx.x;
  const float* mp = M + (size_t)t * 9;
  float m00 = mp[0], m01 = mp[1], m02 = mp[2];
  float m10 = mp[3], m11 = mp[4], m12 = mp[5];
  float m20 = mp[6], m21 = mp[7], m22 = mp[8];

  float Aq[4][4], V[4][4];
  Aq[0][0] =  m00 + m11 + m22;
  Aq[1][1] =  m00 - m11 - m22;
  Aq[2][2] = -m00 + m11 - m22;
  Aq[3][3] = -m00 - m11 + m22;
  Aq[0][1] = Aq[1][0] = m21 - m12;
  Aq[0][2] = Aq[2][0] = m02 - m20;
  Aq[0][3] = Aq[3][0] = m10 - m01;
  Aq[1][2] = Aq[2][1] = m01 + m10;
  Aq[1][3] = Aq[3][1] = m02 + m20;
  Aq[2][3] = Aq[3][2] = m12 + m21;
  #pragma unroll
  for (int i = 0; i < 4; ++i)
    #pragma unroll
    for (int j = 0; j < 4; ++j)
      V[i][j] = (i == j) ? 1.f : 0.f;

  #pragma unroll
  for (int sweep = 0; sweep < 5; ++sweep) {
    jrot<0,1>(Aq, V); jrot<0,2>(Aq, V); jrot<0,3>(Aq, V);
    jrot<1,2>(Aq, V); jrot<1,3>(Aq, V); jrot<2,3>(Aq, V);
  }

  float bv = Aq[0][0];
  float qw = V[0][0], qx = V[1][0], qy = V[2][0], qz = V[3][0];
  #define PICK(K) if (Aq[K][K] > bv) { bv = Aq[K][K]; qw = V[0][K]; qx = V[1][K]; qy = V[2][K]; qz = V[3][K]; }
  PICK(1) PICK(2) PICK(3)
  #undef PICK

  // fp64 Rayleigh-shift + adjugate inverse-iteration refinement
  double d00 = (double)m00, d01 = (double)m01, d02 = (double)m02;
  double d10 = (double)m10, d11 = (double)m11, d12 = (double)m12;
  double d20 = (double)m20, d21 = (double)m21, d22 = (double)m22;
  double Nd[4][4];
  Nd[0][0] =  d00 + d11 + d22;
  Nd[1][1] =  d00 - d11 - d22;
  Nd[2][2] = -d00 + d11 - d22;
  Nd[3][3] = -d00 - d11 + d22;
  Nd[0][1] = Nd[1][0] = d21 - d12;
  Nd[0][2] = Nd[2][0] = d02 - d20;
  Nd[0][3] = Nd[3][0] = d10 - d01;
  Nd[1][2] = Nd[2][1] = d01 + d10;
  Nd[1][3] = Nd[3][1] = d02 + d20;
  Nd[2][3] = Nd[3][2] = d12 + d21;

  double qd[4] = {(double)qw, (double)qx, (double)qy, (double)qz};
  double nn = qd[0]*qd[0] + qd[1]*qd[1] + qd[2]*qd[2] + qd[3]*qd[3];
  double Nq[4];
  #pragma unroll
  for (int i = 0; i < 4; ++i)
    Nq[i] = Nd[i][0]*qd[0] + Nd[i][1]*qd[1] + Nd[i][2]*qd[2] + Nd[i][3]*qd[3];
  double sig = (qd[0]*Nq[0] + qd[1]*Nq[1] + qd[2]*Nq[2] + qd[3]*Nq[3]) / nn;

  double Ad[4][4];
  #pragma unroll
  for (int i = 0; i < 4; ++i)
    #pragma unroll
    for (int j = 0; j < 4; ++j)
      Ad[i][j] = Nd[i][j] - (i == j ? sig : 0.0);

  double y[4];
  #pragma unroll
  for (int i = 0; i < 4; ++i) {
    double yi = 0.0;
    #pragma unroll
    for (int j = 0; j < 4; ++j) {
      const int r0 = (i == 0) ? 1 : 0, r1 = (i <= 1) ? 2 : 1, r2 = (i <= 2) ? 3 : 2;
      const int c0 = (j == 0) ? 1 : 0, c1 = (j <= 1) ? 2 : 1, c2 = (j <= 2) ? 3 : 2;
      double mnr = det3(Ad[r0][c0], Ad[r0][c1], Ad[r0][c2],
                        Ad[r1][c0], Ad[r1][c1], Ad[r1][c2],
                        Ad[r2][c0], Ad[r2][c1], Ad[r2][c2]);
      double s = ((i + j) & 1) ? -mnr : mnr;
      yi += s * qd[j];
    }
    y[i] = yi;
  }
  double yn = y[0]*y[0] + y[1]*y[1] + y[2]*y[2] + y[3]*y[3];
  if (!(yn > 1e-280)) { y[0] = qd[0]; y[1] = qd[1]; y[2] = qd[2]; y[3] = qd[3]; yn = nn; }
  double inv = 1.0 / sqrt(yn);
  double w = y[0]*inv, x = y[1]*inv, yv = y[2]*inv, z = y[3]*inv;

  double xx = x*x, yy = yv*yv, zz = z*z;
  double xy = x*yv, xz = x*z, yz = yv*z;
  double wx = w*x, wy = w*yv, wz = w*z;

  float* op = out + (size_t)t * 9;
  op[0] = (float)(1.0 - 2.0*(yy + zz));
  op[1] = (float)(2.0*(xy - wz));
  op[2] = (float)(2.0*(xz + wy));
  op[3] = (float)(2.0*(xy + wz));
  op[4] = (float)(1.0 - 2.0*(xx + zz));
  op[5] = (float)(2.0*(yz - wx));
  op[6] = (float)(2.0*(xz - wy));
  op[7] = (float)(2.0*(yz + wx));
  op[8] = (float)(1.0 - 2.0*(xx + yy));
}

extern "C" void kernel_launch(void* const* d_in, const int* in_sizes, int n_in,
                              void* d_out, int out_size, void* d_ws, size_t ws_size,
                              hipStream_t stream) {
  const float* bb = (const float*)d_in[0];
  const float* W1 = (const float*)d_in[1];
  const float* b1 = (const float*)d_in[2];
  const float* W2 = (const float*)d_in[3];
  const float* b2 = (const float*)d_in[4];
  float* out = (float*)d_out;
  char* ws = (char*)d_ws;
  // ws: w1h[128K] w1l[128K] w2h[8K] w2l[8K] M[9.44MB]
  unsigned short* w1h = (unsigned short*)(ws);
  unsigned short* w1l = (unsigned short*)(ws + 131072);
  unsigned short* w2h = (unsigned short*)(ws + 262144);
  unsigned short* w2l = (unsigned short*)(ws + 270336);
  float* Mbuf = (float*)(ws + 278528);

  hipLaunchKernelGGL(prep_kernel, dim3(272), dim3(256), 0, stream,
                     W1, W2, w1h, w1l, w2h, w2l);
  hipLaunchKernelGGL(mlp_kernel, dim3(NN / 64), dim3(256), 0, stream,
                     bb, b1, b2, w1h, w1l, w2h, w2l, Mbuf);
  hipLaunchKernelGGL(procrustes_kernel, dim3(NN / 256), dim3(256), 0, stream, Mbuf, out);
}